// Round 20
// baseline (119.906 us; speedup 1.0000x reference)
//
#include <hip/hip_runtime.h>
#include <hip/hip_bf16.h>
#include <math.h>

#define NROWS 19200   // N*L = 4*4800
#define SLEN  4800
#define KV_CHUNKS 75
#define KV_SC     64

typedef unsigned short ushort_t;
typedef __attribute__((ext_vector_type(8))) short bf16x8;
typedef __attribute__((ext_vector_type(4))) float f32x4;
typedef __attribute__((ext_vector_type(8))) unsigned short ushort8;

__device__ __forceinline__ float bf2f(ushort_t u) {
  union { unsigned int i; float f; } x; x.i = ((unsigned int)u) << 16; return x.f;
}
__device__ __forceinline__ ushort_t f2bf(float f) {
  __hip_bfloat16 h = __float2bfloat16(f);
  union { __hip_bfloat16 h; ushort_t u; } x; x.h = h; return x.u;
}

// bijective XCD-chunking swizzle (m204): physical p -> logical tile, so each
// XCD (p%8) owns a contiguous logical chunk (A-panel siblings co-resident).
__device__ __forceinline__ int xcd_swizzle(int bid, int nwg) {
  const int q = nwg >> 3, r = nwg & 7;
  const int x = bid & 7, i = bid >> 3;
  return (x < r) ? x * (q + 1) + i : r * (q + 1) + (x - r) * q + i;
}

#define GLOAD16(g, l) __builtin_amdgcn_global_load_lds( \
    (const __attribute__((address_space(1))) unsigned int*)(g), \
    (__attribute__((address_space(3))) unsigned int*)(l), 16, 0, 0)

// ===== BM=128, BN=128, BK=64 MFMA GEMM, bf16 in/out, 256 threads ===========
// Single-buffered (4 blocks/CU at 35840 B LDS — occupancy wins here).
template <int EPI, bool CONCAT>
__device__ __forceinline__ void gemmT_body(
    const ushort_t* __restrict__ A0, const ushort_t* __restrict__ A1,
    const ushort_t* __restrict__ W, ushort_t* __restrict__ outp,
    int Nn, int K, int bm, int bn, char* smem) {
  const int tid = threadIdx.x;
  const int wave = tid >> 6, lane = tid & 63;
  const int wm = (wave >> 1) * 64, wn = (wave & 1) * 64;
  const int l15 = lane & 15, l4 = lane >> 4;

  f32x4 acc[4][4];
#pragma unroll
  for (int i = 0; i < 4; ++i)
#pragma unroll
    for (int j = 0; j < 4; ++j) acc[i][j] = (f32x4){0.f, 0.f, 0.f, 0.f};

  for (int k0 = 0; k0 < K; k0 += 64) {
    const ushort_t* Asrc;
    int ka;
    if (CONCAT) { Asrc = (k0 < 256) ? A0 : A1; ka = k0 & 255; }
    else        { Asrc = A0; ka = k0; }
#pragma unroll
    for (int c = 0; c < 4; ++c) {
      int ch = c * 4 + wave;
      int o = ch * 1024 + lane * 16;
      int row = o >> 7, g = (o >> 4) & 7;
      const ushort_t* sp =
          Asrc + (size_t)(bm + row) * 256 + ka + ((g ^ (row & 7)) << 3);
      GLOAD16(sp, smem + ch * 1024);
    }
#pragma unroll
    for (int c = 0; c < 4; ++c) {
      int ch = c * 4 + wave;
      int o = ch * 1024 + lane * 16;
      int row = o >> 7, g = (o >> 4) & 7;
      const ushort_t* sp =
          W + (size_t)(bn + row) * K + k0 + ((g ^ (row & 7)) << 3);
      GLOAD16(sp, smem + 16384 + ch * 1024);
    }
    __syncthreads();
#pragma unroll
    for (int kc = 0; kc < 2; ++kc) {
      bf16x8 af[4], bfr[4];
#pragma unroll
      for (int mi = 0; mi < 4; ++mi) {
        int r = wm + mi * 16 + l15;
        int G = kc * 4 + l4;
        af[mi] = *(const bf16x8*)(smem + r * 128 + ((G ^ (r & 7)) << 4));
      }
#pragma unroll
      for (int ni = 0; ni < 4; ++ni) {
        int r = wn + ni * 16 + l15;
        int G = kc * 4 + l4;
        bfr[ni] = *(const bf16x8*)(smem + 16384 + r * 128 +
                                   ((G ^ (r & 7)) << 4));
      }
#pragma unroll
      for (int mi = 0; mi < 4; ++mi)
#pragma unroll
        for (int ni = 0; ni < 4; ++ni)
          acc[mi][ni] = __builtin_amdgcn_mfma_f32_16x16x32_bf16(
              af[mi], bfr[ni], acc[mi][ni], 0, 0, 0);
    }
    __syncthreads();
  }

  ushort_t* st = (ushort_t*)smem;
#pragma unroll
  for (int mi = 0; mi < 4; ++mi)
#pragma unroll
    for (int ni = 0; ni < 4; ++ni)
#pragma unroll
      for (int j = 0; j < 4; ++j) {
        int trow = wm + mi * 16 + l4 * 4 + j;
        int tcol = wn + ni * 16 + l15;
        float v = acc[mi][ni][j];
        if (EPI == 3) v = fmaxf(v, 0.f);
        st[trow * 140 + tcol] = f2bf(v);
      }
  __syncthreads();
#pragma unroll
  for (int c = 0; c < 8; ++c) {
    int ch = c * 256 + tid;
    int row = ch >> 4, g = ch & 15;
    ushort8 u = *(const ushort8*)&st[row * 140 + g * 8];
    *(ushort8*)&outp[(size_t)(bm + row) * Nn + bn + g * 8] = u;
  }
}

// q,k,v pure GEMMs: logical 900: [0,300) q, [300,600) k, [600,900) v.
// XCD swizzle co-locates bn-siblings (shared A-panel) per XCD L2.
__global__ __launch_bounds__(256) void qkv_fused(
    const ushort_t* __restrict__ xb, const ushort_t* __restrict__ srcb,
    const ushort_t* __restrict__ Wqb, const ushort_t* __restrict__ Wkb,
    const ushort_t* __restrict__ Wvb,
    ushort_t* __restrict__ Q, ushort_t* __restrict__ Kb,
    ushort_t* __restrict__ Vb) {
  extern __shared__ char smem[];
  int b = xcd_swizzle(blockIdx.x, 900);
  const int which = b < 300 ? 0 : (b < 600 ? 1 : 2);
  b -= which * 300;
  const int bm = (b >> 1) * 128, bn = (b & 1) * 128;
  const ushort_t* A = (which == 0) ? xb : srcb;
  const ushort_t* W = (which == 0) ? Wqb : (which == 1 ? Wkb : Wvb);
  ushort_t* o = (which == 0) ? Q : (which == 1 ? Kb : Vb);
  gemmT_body<0, false>(A, nullptr, W, o, 256, 256, bm, bn, smem);
}

// MLP1: h1 = relu([xb, msgln] @ W1.T); logical 600 = 150 bm x 4 bn (swizzled)
__global__ __launch_bounds__(256) void mlp1_kernel(
    const ushort_t* __restrict__ xb, const ushort_t* __restrict__ msgln,
    const ushort_t* __restrict__ W1b, ushort_t* __restrict__ h1) {
  extern __shared__ char smem[];
  const int lb = xcd_swizzle(blockIdx.x, 600);
  const int bm = (lb >> 2) * 128, bn = (lb & 3) * 128;
  gemmT_body<3, true>(xb, msgln, W1b, h1, 512, 512, bm, bn, smem);
}

// ==== FUSED: msg (MFMA, KV transposed bf16) + merge GEMM (BK=64) + LN ======
// BM=16, grid 1200, 256 threads. KVt global layout bf16: [nh][v*32+d].
__global__ __launch_bounds__(256) void msg_merge_ln(
    const ushort_t* __restrict__ Qb, const float* __restrict__ x_pe,
    const ushort_t* __restrict__ KVtb, const float* __restrict__ Ksum,
    const ushort_t* __restrict__ Wm,
    const float* __restrict__ g, const float* __restrict__ bb,
    ushort_t* __restrict__ msgln) {
  __shared__ ushort_t AsM[16 * 256];   // 8KB: phiQ bf16 (swz), later msg As
  __shared__ ushort_t U[256 * 64];     // 32KB union: KVl bf16 (16KB) / Bs
  __shared__ float Ks[8][32];
  __shared__ float zS[16][8];
  __shared__ float partS[4][16];
  __shared__ float partQ[4][16];
  __shared__ float gS[256], bS[256];

  const int tid = threadIdx.x;
  const int wave = tid >> 6, lane = tid & 63;
  const int l15 = lane & 15, l4 = lane >> 4;
  const int bm = blockIdx.x * 16;
  const int n = bm / SLEN;

  gS[tid] = g[tid];
  bS[tid] = bb[tid];
  Ks[tid >> 5][tid & 31] = Ksum[(n * 8 + (tid >> 5)) * 32 + (tid & 31)];
  __syncthreads();   // Ks visible to ALL waves before z-partials read it

  // ---- stage KVl via async GLOAD16, pre-swizzled source ----
  ushort_t* KVl = U;
#pragma unroll
  for (int c = 0; c < 4; ++c) {
    int ch = c * 256 + tid;            // 1024 chunks of 16B
    int e = ch * 8;
    int h = e >> 10, v = (e >> 5) & 31, gd = (e >> 3) & 3;
    int gsw = gd ^ ((v >> 1) & 3);
    GLOAD16(KVtb + (size_t)(n * 8) * 1024 + h * 1024 + v * 32 + gsw * 8,
            (char*)KVl + ch * 16);
  }

  // ---- stage Q: rotary + phi -> AsM (swz) + z partial via shfl ----
#pragma unroll
  for (int p = 0; p < 2; ++p) {
    int rr = p * 8 + (tid >> 5), cc = (tid & 31) * 8;
    const size_t eoff = (size_t)(bm + rr) * 256 + cc;
    const ushort8 uq = *(const ushort8*)&Qb[eoff];
    const float4* pp = (const float4*)&x_pe[eoff * 2];
    float4 p0 = pp[0], p1 = pp[1], p2 = pp[2], p3 = pp[3];
    float v[8];
#pragma unroll
    for (int i = 0; i < 8; ++i) v[i] = bf2f((ushort_t)uq[i]);
    float r[8];
    r[0] = v[0] * p0.x - v[1] * p0.y; r[1] = v[1] * p0.z + v[0] * p0.w;
    r[2] = v[2] * p1.x - v[3] * p1.y; r[3] = v[3] * p1.z + v[2] * p1.w;
    r[4] = v[4] * p2.x - v[5] * p2.y; r[5] = v[5] * p2.z + v[4] * p2.w;
    r[6] = v[6] * p3.x - v[7] * p3.y; r[7] = v[7] * p3.z + v[6] * p3.w;
    float w[8];
    ushort8 pk;
#pragma unroll
    for (int i = 0; i < 8; ++i) {
      w[i] = r[i] > 0.f ? r[i] + 1.f : __expf(r[i]);
      pk[i] = f2bf(w[i]);
    }
    int gi = cc >> 3;
    int gis = (gi & ~7) | ((gi & 7) ^ (rr & 7));
    *(ushort8*)&AsM[rr * 256 + gis * 8] = pk;
    const int hh = (tid & 31) >> 2;
    const int db = (tid & 3) * 8;
    float zp = 0.f;
#pragma unroll
    for (int i = 0; i < 8; ++i) zp += w[i] * Ks[hh][db + i];
    zp += __shfl_xor(zp, 1);
    zp += __shfl_xor(zp, 2);
    if ((tid & 3) == 0) zS[rr][hh] = 1.0f / (zp + 1e-6f);
  }
  __syncthreads();   // drains vmcnt too: KVl valid past here

  // ---- msg via MFMA: wave handles heads 2w, 2w+1; M=16 ----
  f32x4 macc[2][2];
#pragma unroll
  for (int hh2 = 0; hh2 < 2; ++hh2) {
    const int h = wave * 2 + hh2;
    bf16x8 af, bfr[2];
    {
      int r = l15;
      int gi = h * 4 + l4;
      int gis = (gi & ~7) | ((gi & 7) ^ (r & 7));
      af = *(const bf16x8*)&AsM[r * 256 + gis * 8];
    }
#pragma unroll
    for (int ni = 0; ni < 2; ++ni) {
      int v = ni * 16 + l15;
      int gsw = l4 ^ ((v >> 1) & 3);
      bfr[ni] = *(const bf16x8*)&KVl[h * 1024 + v * 32 + gsw * 8];
    }
#pragma unroll
    for (int ni = 0; ni < 2; ++ni)
      macc[hh2][ni] = __builtin_amdgcn_mfma_f32_16x16x32_bf16(
          af, bfr[ni], (f32x4){0.f, 0.f, 0.f, 0.f}, 0, 0, 0);
  }
  __syncthreads();

  // ---- scale by z, write msg back into AsM (GEMM-A swizzled layout) ----
#pragma unroll
  for (int hh2 = 0; hh2 < 2; ++hh2) {
    const int h = wave * 2 + hh2;
#pragma unroll
    for (int ni = 0; ni < 2; ++ni)
#pragma unroll
      for (int j = 0; j < 4; ++j) {
        int row = l4 * 4 + j;
        int col = h * 32 + ni * 16 + l15;
        float mv = macc[hh2][ni][j] * zS[row][h];
        int gi = col >> 3;
        int gis = (gi & ~7) | ((gi & 7) ^ (row & 7));
        AsM[row * 256 + gis * 8 + (col & 7)] = f2bf(mv);
      }
  }

  // ---- merge GEMM: msg @ Wm.T, BK=64 (Bs in union over KVl) ----
  ushort_t* Bs = U;
  f32x4 acc[4];
#pragma unroll
  for (int j = 0; j < 4; ++j) acc[j] = (f32x4){0.f, 0.f, 0.f, 0.f};

  for (int k0 = 0; k0 < 256; k0 += 64) {
#pragma unroll
    for (int c = 0; c < 8; ++c) {
      int ch = c * 256 + tid;
      int row = ch >> 3, gch = ch & 7;
      const ushort_t* src =
          Wm + (size_t)row * 256 + k0 + ((gch ^ (row & 7)) << 3);
      GLOAD16(src, (char*)Bs + ch * 16);
    }
    __syncthreads();
#pragma unroll
    for (int kc = 0; kc < 2; ++kc) {
      bf16x8 af, bfr[4];
      {
        int r = l15;
        int gi = (k0 >> 3) + kc * 4 + l4;
        int gis = (gi & ~7) | ((gi & 7) ^ (r & 7));
        af = *(const bf16x8*)&AsM[r * 256 + gis * 8];
      }
#pragma unroll
      for (int ni = 0; ni < 4; ++ni) {
        int r = wave * 64 + ni * 16 + l15;
        int G = kc * 4 + l4;
        bfr[ni] = *(const bf16x8*)((char*)Bs + r * 128 + ((G ^ (r & 7)) << 4));
      }
#pragma unroll
      for (int ni = 0; ni < 4; ++ni)
        acc[ni] = __builtin_amdgcn_mfma_f32_16x16x32_bf16(
            af, bfr[ni], acc[ni], 0, 0, 0);
    }
    __syncthreads();
  }

  // ---- row LayerNorm across the 4 waves ----
#pragma unroll
  for (int j = 0; j < 4; ++j) {
    float s = acc[0][j] + acc[1][j] + acc[2][j] + acc[3][j];
    float q = acc[0][j] * acc[0][j] + acc[1][j] * acc[1][j] +
              acc[2][j] * acc[2][j] + acc[3][j] * acc[3][j];
#pragma unroll
    for (int m = 1; m < 16; m <<= 1) {
      s += __shfl_xor(s, m);
      q += __shfl_xor(q, m);
    }
    if (l15 == 0) {
      int row = l4 * 4 + j;
      partS[wave][row] = s;
      partQ[wave][row] = q;
    }
  }
  __syncthreads();

  float mu[4], rsv[4];
#pragma unroll
  for (int j = 0; j < 4; ++j) {
    int row = l4 * 4 + j;
    float s = partS[0][row] + partS[1][row] + partS[2][row] + partS[3][row];
    float q2 = partQ[0][row] + partQ[1][row] + partQ[2][row] + partQ[3][row];
    float m_ = s * (1.f / 256.f);
    float var = q2 * (1.f / 256.f) - m_ * m_;
    mu[j] = m_;
    rsv[j] = rsqrtf(var + 1e-5f);
  }

#pragma unroll
  for (int ni = 0; ni < 4; ++ni)
#pragma unroll
    for (int j = 0; j < 4; ++j) {
      int row = l4 * 4 + j;
      int col2 = wave * 64 + ni * 16 + l15;
      float vv = (acc[ni][j] - mu[j]) * rsv[j] * gS[col2] + bS[col2];
      msgln[(size_t)(bm + row) * 256 + col2] = f2bf(vv);
    }
}

// ------- Fused GEMM (out = A @ W.T) + row LayerNorm (+residual) -------------
template <int KDIM, bool RESID, bool OUTBF>
__global__ __launch_bounds__(256) void gemm_ln_kernel(
    const ushort_t* __restrict__ A, const ushort_t* __restrict__ W,
    const float* __restrict__ g, const float* __restrict__ bb,
    const float* __restrict__ resid, void* __restrict__ outp) {
  __shared__ char As[32 * 128];
  __shared__ char Bs[256 * 128];
  __shared__ float partS[4][32];
  __shared__ float partQ[4][32];
  __shared__ float gS[256], bS[256];

  const int tid = threadIdx.x;
  const int wave = tid >> 6, lane = tid & 63;
  const int l15 = lane & 15, l4 = lane >> 4;
  const int bm = blockIdx.x * 32;

  gS[tid] = g[tid];
  bS[tid] = bb[tid];

  f32x4 acc[2][4];
#pragma unroll
  for (int i = 0; i < 2; ++i)
#pragma unroll
    for (int j = 0; j < 4; ++j) acc[i][j] = (f32x4){0.f, 0.f, 0.f, 0.f};

  for (int k0 = 0; k0 < KDIM; k0 += 64) {
    {
      int row = tid >> 3, gch = tid & 7;
      const ushort_t* src =
          A + (size_t)(bm + row) * KDIM + k0 + ((gch ^ (row & 7)) << 3);
      GLOAD16(src, As + tid * 16);
    }
#pragma unroll
    for (int c = 0; c < 8; ++c) {
      int ch = c * 256 + tid;
      int row = ch >> 3, gch = ch & 7;
      const ushort_t* src =
          W + (size_t)row * KDIM + k0 + ((gch ^ (row & 7)) << 3);
      GLOAD16(src, Bs + ch * 16);
    }
    __syncthreads();
#pragma unroll
    for (int kc = 0; kc < 2; ++kc) {
      bf16x8 af[2], bfr[4];
#pragma unroll
      for (int mi = 0; mi < 2; ++mi) {
        int r = mi * 16 + l15;
        int G = kc * 4 + l4;
        af[mi] = *(const bf16x8*)(As + r * 128 + ((G ^ (r & 7)) << 4));
      }
#pragma unroll
      for (int ni = 0; ni < 4; ++ni) {
        int r = wave * 64 + ni * 16 + l15;
        int G = kc * 4 + l4;
        bfr[ni] = *(const bf16x8*)(Bs + r * 128 + ((G ^ (r & 7)) << 4));
      }
#pragma unroll
      for (int mi = 0; mi < 2; ++mi)
#pragma unroll
        for (int ni = 0; ni < 4; ++ni)
          acc[mi][ni] = __builtin_amdgcn_mfma_f32_16x16x32_bf16(
              af[mi], bfr[ni], acc[mi][ni], 0, 0, 0);
    }
    __syncthreads();
  }

#pragma unroll
  for (int mi = 0; mi < 2; ++mi)
#pragma unroll
    for (int j = 0; j < 4; ++j) {
      float s = acc[mi][0][j] + acc[mi][1][j] + acc[mi][2][j] + acc[mi][3][j];
      float q = acc[mi][0][j] * acc[mi][0][j] + acc[mi][1][j] * acc[mi][1][j] +
                acc[mi][2][j] * acc[mi][2][j] + acc[mi][3][j] * acc[mi][3][j];
#pragma unroll
      for (int m = 1; m < 16; m <<= 1) {
        s += __shfl_xor(s, m);
        q += __shfl_xor(q, m);
      }
      if (l15 == 0) {
        int row = mi * 16 + l4 * 4 + j;
        partS[wave][row] = s;
        partQ[wave][row] = q;
      }
    }
  __syncthreads();

  float mu[2][4], rsv[2][4];
#pragma unroll
  for (int mi = 0; mi < 2; ++mi)
#pragma unroll
    for (int j = 0; j < 4; ++j) {
      int row = mi * 16 + l4 * 4 + j;
      float s = partS[0][row] + partS[1][row] + partS[2][row] + partS[3][row];
      float q2 = partQ[0][row] + partQ[1][row] + partQ[2][row] + partQ[3][row];
      float m_ = s * (1.f / 256.f);
      float var = q2 * (1.f / 256.f) - m_ * m_;
      mu[mi][j] = m_;
      rsv[mi][j] = rsqrtf(var + 1e-5f);
    }

#pragma unroll
  for (int mi = 0; mi < 2; ++mi)
#pragma unroll
    for (int ni = 0; ni < 4; ++ni)
#pragma unroll
      for (int j = 0; j < 4; ++j) {
        int row = mi * 16 + l4 * 4 + j;
        int col = wave * 64 + ni * 16 + l15;
        float v = (acc[mi][ni][j] - mu[mi][j]) * rsv[mi][j] * gS[col] + bS[col];
        size_t gr = (size_t)(bm + row);
        if (RESID) v += resid[gr * 256 + col];
        if (OUTBF)
          ((ushort_t*)outp)[gr * 256 + col] = f2bf(v);
        else
          ((float*)outp)[gr * 256 + col] = v;
      }
}

// ---- KV = sum_s phi(rot(K))^T V, Ksum = sum_s phi(rot(K)); rot fused ------
// grid 2400 = 32 (n,h) x 75 chunks of 64 s-rows (2 iters of 32).
__global__ __launch_bounds__(256) void kv_partial(
    const ushort_t* __restrict__ Kb, const ushort_t* __restrict__ Vb,
    const float* __restrict__ s_pe,
    float* __restrict__ kvp, float* __restrict__ ksp) {
  __shared__ float bufK[32][32];
  __shared__ float bufV[32][32];
  const int b = blockIdx.x;
  const int ch = b % KV_CHUNKS;
  const int nh = b / KV_CHUNKS;
  const int h = nh & 7, n = nh >> 3;
  const int tid = threadIdx.x;
  const int d = tid >> 3, vb = (tid & 7) * 4;
  const int half = tid >> 7, t = tid & 127;
  const int srow = t >> 2, seg = (t & 3) * 8;
  const int segS = (seg + 8 * (srow & 3)) & 31;
  float a0 = 0.f, a1 = 0.f, a2 = 0.f, a3 = 0.f, ks = 0.f;
  const size_t base = (size_t)n * SLEN * 256 + (size_t)h * 32;
  const int s0 = ch * KV_SC;
  for (int s = s0; s < s0 + KV_SC; s += 32) {
    __syncthreads();
    const size_t eoff = base + (size_t)(s + srow) * 256 + seg;
    ushort8 u = *(const ushort8*)((half ? Vb : Kb) + eoff);
    float v[8];
#pragma unroll
    for (int i = 0; i < 8; ++i) v[i] = bf2f((ushort_t)u[i]);
    if (!half) {
      const float4* pp = (const float4*)&s_pe[eoff * 2];
      float4 p0 = pp[0], p1 = pp[1], p2 = pp[2], p3 = pp[3];
      float r[8];
      r[0] = v[0] * p0.x - v[1] * p0.y; r[1] = v[1] * p0.z + v[0] * p0.w;
      r[2] = v[2] * p1.x - v[3] * p1.y; r[3] = v[3] * p1.z + v[2] * p1.w;
      r[4] = v[4] * p2.x - v[5] * p2.y; r[5] = v[5] * p2.z + v[4] * p2.w;
      r[6] = v[6] * p3.x - v[7] * p3.y; r[7] = v[7] * p3.z + v[6] * p3.w;
#pragma unroll
      for (int i = 0; i < 8; ++i)
        v[i] = r[i] > 0.f ? r[i] + 1.f : __expf(r[i]);
    }
    float* dst = half ? &bufV[srow][segS] : &bufK[srow][segS];
    *(float4*)dst = (float4){v[0], v[1], v[2], v[3]};
    *(float4*)(dst + 4) = (float4){v[4], v[5], v[6], v[7]};
    __syncthreads();
#pragma unroll
    for (int ss = 0; ss < 32; ++ss) {
      int rot = 8 * (ss & 3);
      float kd = bufK[ss][(d + rot) & 31];
      float4 vv = *(const float4*)&bufV[ss][(vb + rot) & 31];
      a0 += kd * vv.x; a1 += kd * vv.y; a2 += kd * vv.z; a3 += kd * vv.w;
      ks += kd;
    }
  }
  float* kv = &kvp[(size_t)b * 1024 + d * 32 + vb];
  kv[0] = a0; kv[1] = a1; kv[2] = a2; kv[3] = a3;
  if ((tid & 7) == 0) ksp[(size_t)b * 32 + d] = ks;
}

// reduce partials; output KV TRANSPOSED bf16: KVtb[nh][v*32+d]
__global__ __launch_bounds__(256) void kv_reduce(
    const float* __restrict__ kvp, const float* __restrict__ ksp,
    ushort_t* __restrict__ KVtb, float* __restrict__ Ksum) {
  const int nh = blockIdx.x;
  const int tid = threadIdx.x;
  for (int e = tid; e < 1024; e += 256) {   // e = d*32 + v (source layout)
    float s = 0.f;
    for (int p = 0; p < KV_CHUNKS; ++p)
      s += kvp[(size_t)(nh * KV_CHUNKS + p) * 1024 + e];
    KVtb[(size_t)nh * 1024 + (e & 31) * 32 + (e >> 5)] = f2bf(s);
  }
  if (tid < 32) {
    float s = 0.f;
    for (int p = 0; p < KV_CHUNKS; ++p)
      s += ksp[(size_t)(nh * KV_CHUNKS + p) * 32 + tid];
    Ksum[nh * 32 + tid] = s;
  }
}

// ------- fp32 -> bf16 conversions, one dispatch: [0,4800) x/src, rest W -----
__global__ __launch_bounds__(256) void conv_all(
    const float* __restrict__ x, const float* __restrict__ src,
    const float* w0, const float* w1, const float* w2, const float* w3,
    const float* w4, const float* w5,
    ushort_t* __restrict__ xo, ushort_t* __restrict__ so,
    ushort_t* o0, ushort_t* o1, ushort_t* o2, ushort_t* o3, ushort_t* o4,
    ushort_t* o5) {
  int blk = blockIdx.x;
  if (blk < 4800) {
    const float* s; ushort_t* d;
    if (blk < 2400) { s = x; d = xo; } else { s = src; d = so; blk -= 2400; }
    size_t o = ((size_t)blk * 256 + threadIdx.x) * 8;
    float4 v0 = *(const float4*)&s[o];
    float4 v1 = *(const float4*)&s[o + 4];
    ushort8 u = {f2bf(v0.x), f2bf(v0.y), f2bf(v0.z), f2bf(v0.w),
                 f2bf(v1.x), f2bf(v1.y), f2bf(v1.z), f2bf(v1.w)};
    *(ushort8*)&d[o] = u;
  } else {
    int e = ((blk - 4800) * 256 + threadIdx.x) * 4;
    const float* s; ushort_t* d; int off;
    if      (e < 65536)  { s = w0; d = o0; off = e; }
    else if (e < 131072) { s = w1; d = o1; off = e - 65536; }
    else if (e < 196608) { s = w2; d = o2; off = e - 131072; }
    else if (e < 262144) { s = w3; d = o3; off = e - 196608; }
    else if (e < 524288) { s = w4; d = o4; off = e - 262144; }
    else                 { s = w5; d = o5; off = e - 524288; }
    float4 v = *(const float4*)&s[off];
    ushort4 u = make_ushort4(f2bf(v.x), f2bf(v.y), f2bf(v.z), f2bf(v.w));
    *(ushort4*)&d[off] = u;
  }
}

extern "C" void kernel_launch(void* const* d_in, const int* in_sizes, int n_in,
                              void* d_out, int out_size, void* d_ws,
                              size_t ws_size, hipStream_t stream) {
  const float* x    = (const float*)d_in[0];
  const float* src  = (const float*)d_in[1];
  const float* x_pe = (const float*)d_in[2];
  const float* s_pe = (const float*)d_in[3];
  const float* Wq = (const float*)d_in[4];
  const float* Wk = (const float*)d_in[5];
  const float* Wv = (const float*)d_in[6];
  const float* Wm = (const float*)d_in[7];
  const float* W1 = (const float*)d_in[8];
  const float* W2 = (const float*)d_in[9];
  const float* g1 = (const float*)d_in[10];
  const float* b1 = (const float*)d_in[11];
  const float* g2 = (const float*)d_in[12];
  const float* b2 = (const float*)d_in[13];
  float* out = (float*)d_out;

  const size_t R = (size_t)NROWS * 256;  // 4,915,200
  ushort_t* xb    = (ushort_t*)d_ws;
  ushort_t* srcb  = xb + R;
  ushort_t* Qb    = srcb + R;
  ushort_t* Kb    = Qb + R;
  ushort_t* Vb    = Kb + R;
  ushort_t* msgln = Vb + R;
  ushort_t* Wqb   = msgln + R;
  ushort_t* Wkb   = Wqb + 65536;
  ushort_t* Wvb   = Wkb + 65536;
  ushort_t* Wmb   = Wvb + 65536;
  ushort_t* W1b   = Wmb + 65536;
  ushort_t* W2b   = W1b + 262144;
  float* kvp      = (float*)(W2b + 131072);   // 2400*1024 f32
  float* ksp      = kvp + 2457600;            // 76800
  ushort_t* KVtb  = (ushort_t*)(ksp + 76800); // 32768 bf16
  float* Ksum     = (float*)(KVtb + 32768);   // 1024
  ushort_t* h1   = Kb;     // Kb+Vb dead after kv_partial (2R contiguous)

  dim3 blk(256);
  conv_all<<<5440, blk, 0, stream>>>(x, src, Wq, Wk, Wv, Wm, W1, W2,
                                     xb, srcb, Wqb, Wkb, Wvb, Wmb, W1b, W2b);
  // q,k,v pure GEMMs (single-buffer, XCD-swizzled)
  qkv_fused<<<900, blk, 35840, stream>>>(xb, srcb, Wqb, Wkb, Wvb, Qb, Kb, Vb);
  // KV/Ksum with rotary+phi fused on K staging (75 chunks)
  kv_partial<<<2400, blk, 0, stream>>>(Kb, Vb, s_pe, kvp, ksp);
  kv_reduce<<<32, blk, 0, stream>>>(kvp, ksp, KVtb, Ksum);
  // FUSED: msg (MFMA, transposed bf16 KV) + merge GEMM + LN1 -> msgln (bf16)
  msg_merge_ln<<<1200, blk, 0, stream>>>(Qb, x_pe, KVtb, Ksum, Wmb, g1, b1,
                                         msgln);
  // MLP1: h1 = relu([xb, msgln] @ W1.T) (bf16, XCD-swizzled)
  mlp1_kernel<<<600, blk, 35840, stream>>>(xb, msgln, W1b, h1);
  // MLP2 + LN2 + residual: out = x + LN(h1 @ W2.T) (fp32)
  gemm_ln_kernel<512, true, false><<<600, blk, 0, stream>>>(
      h1, W2b, g2, b2, x, out);
}

// Round 21
// 117.352 us; speedup vs baseline: 1.0218x; 1.0218x over previous
//
#include <hip/hip_runtime.h>
#include <hip/hip_bf16.h>
#include <math.h>

#define NROWS 19200   // N*L = 4*4800
#define SLEN  4800
#define KV_CHUNKS 50
#define KV_SC     96

typedef unsigned short ushort_t;
typedef __attribute__((ext_vector_type(8))) short bf16x8;
typedef __attribute__((ext_vector_type(4))) float f32x4;
typedef __attribute__((ext_vector_type(8))) unsigned short ushort8;

__device__ __forceinline__ float bf2f(ushort_t u) {
  union { unsigned int i; float f; } x; x.i = ((unsigned int)u) << 16; return x.f;
}
__device__ __forceinline__ ushort_t f2bf(float f) {
  __hip_bfloat16 h = __float2bfloat16(f);
  union { __hip_bfloat16 h; ushort_t u; } x; x.h = h; return x.u;
}

#define GLOAD16(g, l) __builtin_amdgcn_global_load_lds( \
    (const __attribute__((address_space(1))) unsigned int*)(g), \
    (__attribute__((address_space(3))) unsigned int*)(l), 16, 0, 0)

// ===== BM=128, BN=128, BK=64 MFMA GEMM, bf16 in/out, 256 threads ===========
// Single-buffered (4 blocks/CU at 35840 B LDS — occupancy wins here).
template <int EPI, bool CONCAT>
__device__ __forceinline__ void gemmT_body(
    const ushort_t* __restrict__ A0, const ushort_t* __restrict__ A1,
    const ushort_t* __restrict__ W, ushort_t* __restrict__ outp,
    int Nn, int K, int bm, int bn, char* smem) {
  const int tid = threadIdx.x;
  const int wave = tid >> 6, lane = tid & 63;
  const int wm = (wave >> 1) * 64, wn = (wave & 1) * 64;
  const int l15 = lane & 15, l4 = lane >> 4;

  f32x4 acc[4][4];
#pragma unroll
  for (int i = 0; i < 4; ++i)
#pragma unroll
    for (int j = 0; j < 4; ++j) acc[i][j] = (f32x4){0.f, 0.f, 0.f, 0.f};

  for (int k0 = 0; k0 < K; k0 += 64) {
    const ushort_t* Asrc;
    int ka;
    if (CONCAT) { Asrc = (k0 < 256) ? A0 : A1; ka = k0 & 255; }
    else        { Asrc = A0; ka = k0; }
#pragma unroll
    for (int c = 0; c < 4; ++c) {
      int ch = c * 4 + wave;
      int o = ch * 1024 + lane * 16;
      int row = o >> 7, g = (o >> 4) & 7;
      const ushort_t* sp =
          Asrc + (size_t)(bm + row) * 256 + ka + ((g ^ (row & 7)) << 3);
      GLOAD16(sp, smem + ch * 1024);
    }
#pragma unroll
    for (int c = 0; c < 4; ++c) {
      int ch = c * 4 + wave;
      int o = ch * 1024 + lane * 16;
      int row = o >> 7, g = (o >> 4) & 7;
      const ushort_t* sp =
          W + (size_t)(bn + row) * K + k0 + ((g ^ (row & 7)) << 3);
      GLOAD16(sp, smem + 16384 + ch * 1024);
    }
    __syncthreads();
#pragma unroll
    for (int kc = 0; kc < 2; ++kc) {
      bf16x8 af[4], bfr[4];
#pragma unroll
      for (int mi = 0; mi < 4; ++mi) {
        int r = wm + mi * 16 + l15;
        int G = kc * 4 + l4;
        af[mi] = *(const bf16x8*)(smem + r * 128 + ((G ^ (r & 7)) << 4));
      }
#pragma unroll
      for (int ni = 0; ni < 4; ++ni) {
        int r = wn + ni * 16 + l15;
        int G = kc * 4 + l4;
        bfr[ni] = *(const bf16x8*)(smem + 16384 + r * 128 +
                                   ((G ^ (r & 7)) << 4));
      }
#pragma unroll
      for (int mi = 0; mi < 4; ++mi)
#pragma unroll
        for (int ni = 0; ni < 4; ++ni)
          acc[mi][ni] = __builtin_amdgcn_mfma_f32_16x16x32_bf16(
              af[mi], bfr[ni], acc[mi][ni], 0, 0, 0);
    }
    __syncthreads();
  }

  ushort_t* st = (ushort_t*)smem;
#pragma unroll
  for (int mi = 0; mi < 4; ++mi)
#pragma unroll
    for (int ni = 0; ni < 4; ++ni)
#pragma unroll
      for (int j = 0; j < 4; ++j) {
        int trow = wm + mi * 16 + l4 * 4 + j;
        int tcol = wn + ni * 16 + l15;
        float v = acc[mi][ni][j];
        if (EPI == 3) v = fmaxf(v, 0.f);
        st[trow * 140 + tcol] = f2bf(v);
      }
  __syncthreads();
#pragma unroll
  for (int c = 0; c < 8; ++c) {
    int ch = c * 256 + tid;
    int row = ch >> 4, g = ch & 15;
    ushort8 u = *(const ushort8*)&st[row * 140 + g * 8];
    *(ushort8*)&outp[(size_t)(bm + row) * Nn + bn + g * 8] = u;
  }
}

// q,k,v pure GEMMs: grid 900: [0,300) q, [300,600) k, [600,900) v
__global__ __launch_bounds__(256) void qkv_fused(
    const ushort_t* __restrict__ xb, const ushort_t* __restrict__ srcb,
    const ushort_t* __restrict__ Wqb, const ushort_t* __restrict__ Wkb,
    const ushort_t* __restrict__ Wvb,
    ushort_t* __restrict__ Q, ushort_t* __restrict__ Kb,
    ushort_t* __restrict__ Vb) {
  extern __shared__ char smem[];
  int b = blockIdx.x;
  const int which = b < 300 ? 0 : (b < 600 ? 1 : 2);
  b -= which * 300;
  const int bm = (b >> 1) * 128, bn = (b & 1) * 128;
  const ushort_t* A = (which == 0) ? xb : srcb;
  const ushort_t* W = (which == 0) ? Wqb : (which == 1 ? Wkb : Wvb);
  ushort_t* o = (which == 0) ? Q : (which == 1 ? Kb : Vb);
  gemmT_body<0, false>(A, nullptr, W, o, 256, 256, bm, bn, smem);
}

// MLP1: h1 = relu([xb, msgln] @ W1.T); grid 600 = 150 bm x 4 bn
__global__ __launch_bounds__(256) void mlp1_kernel(
    const ushort_t* __restrict__ xb, const ushort_t* __restrict__ msgln,
    const ushort_t* __restrict__ W1b, ushort_t* __restrict__ h1) {
  extern __shared__ char smem[];
  const int bm = (blockIdx.x >> 2) * 128, bn = (blockIdx.x & 3) * 128;
  gemmT_body<3, true>(xb, msgln, W1b, h1, 512, 512, bm, bn, smem);
}

// ==== FUSED: msg (MFMA, fp32 KVt staged->bf16) + merge GEMM (BK=64) + LN ====
// BM=16, grid 1200, 256 threads. KVt global layout fp32: [nh][v*32+d].
__global__ __launch_bounds__(256) void msg_merge_ln(
    const ushort_t* __restrict__ Qb, const float* __restrict__ x_pe,
    const float* __restrict__ KVt, const float* __restrict__ Ksum,
    const ushort_t* __restrict__ Wm,
    const float* __restrict__ g, const float* __restrict__ bb,
    ushort_t* __restrict__ msgln) {
  __shared__ ushort_t AsM[16 * 256];   // 8KB: phiQ bf16 (swz), later msg As
  __shared__ ushort_t U[256 * 64];     // 32KB union: KVl bf16 (16KB) / Bs
  __shared__ float Ks[8][32];
  __shared__ float zS[16][8];
  __shared__ float partS[4][16];
  __shared__ float partQ[4][16];
  __shared__ float gS[256], bS[256];

  const int tid = threadIdx.x;
  const int wave = tid >> 6, lane = tid & 63;
  const int l15 = lane & 15, l4 = lane >> 4;
  const int bm = blockIdx.x * 16;
  const int n = bm / SLEN;

  gS[tid] = g[tid];
  bS[tid] = bb[tid];
  Ks[tid >> 5][tid & 31] = Ksum[(n * 8 + (tid >> 5)) * 32 + (tid & 31)];

  // ---- stage KVt (fp32, atomically accumulated) -> bf16 swizzled LDS ----
  ushort_t* KVl = U;
#pragma unroll
  for (int c = 0; c < 8; ++c) {
    int e4 = c * 256 + tid;  // 2048 float4s
    const float4 kv4 = *(const float4*)&KVt[(size_t)(n * 8) * 1024 + e4 * 4];
    int E = e4 * 4;
    int h = E >> 10, v = (E >> 5) & 31, d0 = E & 31;
    int gsw = (d0 >> 3) ^ ((v >> 1) & 3);
    ushort4 u = make_ushort4(f2bf(kv4.x), f2bf(kv4.y), f2bf(kv4.z),
                             f2bf(kv4.w));
    *(ushort4*)&KVl[h * 1024 + v * 32 + gsw * 8 + (d0 & 7)] = u;
  }
  __syncthreads();   // Ks + KVl visible to all waves

  // ---- stage Q: rotary + phi -> AsM (swz) + z partial via shfl ----
#pragma unroll
  for (int p = 0; p < 2; ++p) {
    int rr = p * 8 + (tid >> 5), cc = (tid & 31) * 8;
    const size_t eoff = (size_t)(bm + rr) * 256 + cc;
    const ushort8 uq = *(const ushort8*)&Qb[eoff];
    const float4* pp = (const float4*)&x_pe[eoff * 2];
    float4 p0 = pp[0], p1 = pp[1], p2 = pp[2], p3 = pp[3];
    float v[8];
#pragma unroll
    for (int i = 0; i < 8; ++i) v[i] = bf2f((ushort_t)uq[i]);
    float r[8];
    r[0] = v[0] * p0.x - v[1] * p0.y; r[1] = v[1] * p0.z + v[0] * p0.w;
    r[2] = v[2] * p1.x - v[3] * p1.y; r[3] = v[3] * p1.z + v[2] * p1.w;
    r[4] = v[4] * p2.x - v[5] * p2.y; r[5] = v[5] * p2.z + v[4] * p2.w;
    r[6] = v[6] * p3.x - v[7] * p3.y; r[7] = v[7] * p3.z + v[6] * p3.w;
    float w[8];
    ushort8 pk;
#pragma unroll
    for (int i = 0; i < 8; ++i) {
      w[i] = r[i] > 0.f ? r[i] + 1.f : __expf(r[i]);
      pk[i] = f2bf(w[i]);
    }
    int gi = cc >> 3;
    int gis = (gi & ~7) | ((gi & 7) ^ (rr & 7));
    *(ushort8*)&AsM[rr * 256 + gis * 8] = pk;
    const int hh = (tid & 31) >> 2;
    const int db = (tid & 3) * 8;
    float zp = 0.f;
#pragma unroll
    for (int i = 0; i < 8; ++i) zp += w[i] * Ks[hh][db + i];
    zp += __shfl_xor(zp, 1);
    zp += __shfl_xor(zp, 2);
    if ((tid & 3) == 0) zS[rr][hh] = 1.0f / (zp + 1e-6f);
  }
  __syncthreads();

  // ---- msg via MFMA: wave handles heads 2w, 2w+1; M=16 ----
  f32x4 macc[2][2];
#pragma unroll
  for (int hh2 = 0; hh2 < 2; ++hh2) {
    const int h = wave * 2 + hh2;
    bf16x8 af, bfr[2];
    {
      int r = l15;
      int gi = h * 4 + l4;
      int gis = (gi & ~7) | ((gi & 7) ^ (r & 7));
      af = *(const bf16x8*)&AsM[r * 256 + gis * 8];
    }
#pragma unroll
    for (int ni = 0; ni < 2; ++ni) {
      int v = ni * 16 + l15;
      int gsw = l4 ^ ((v >> 1) & 3);
      bfr[ni] = *(const bf16x8*)&KVl[h * 1024 + v * 32 + gsw * 8];
    }
#pragma unroll
    for (int ni = 0; ni < 2; ++ni)
      macc[hh2][ni] = __builtin_amdgcn_mfma_f32_16x16x32_bf16(
          af, bfr[ni], (f32x4){0.f, 0.f, 0.f, 0.f}, 0, 0, 0);
  }
  __syncthreads();

  // ---- scale by z, write msg back into AsM (GEMM-A swizzled layout) ----
#pragma unroll
  for (int hh2 = 0; hh2 < 2; ++hh2) {
    const int h = wave * 2 + hh2;
#pragma unroll
    for (int ni = 0; ni < 2; ++ni)
#pragma unroll
      for (int j = 0; j < 4; ++j) {
        int row = l4 * 4 + j;
        int col = h * 32 + ni * 16 + l15;
        float mv = macc[hh2][ni][j] * zS[row][h];
        int gi = col >> 3;
        int gis = (gi & ~7) | ((gi & 7) ^ (row & 7));
        AsM[row * 256 + gis * 8 + (col & 7)] = f2bf(mv);
      }
  }

  // ---- merge GEMM: msg @ Wm.T, BK=64 (Bs in union over KVl) ----
  ushort_t* Bs = U;
  f32x4 acc[4];
#pragma unroll
  for (int j = 0; j < 4; ++j) acc[j] = (f32x4){0.f, 0.f, 0.f, 0.f};

  for (int k0 = 0; k0 < 256; k0 += 64) {
#pragma unroll
    for (int c = 0; c < 8; ++c) {
      int ch = c * 256 + tid;
      int row = ch >> 3, gch = ch & 7;
      const ushort_t* src =
          Wm + (size_t)row * 256 + k0 + ((gch ^ (row & 7)) << 3);
      GLOAD16(src, (char*)Bs + ch * 16);
    }
    __syncthreads();
#pragma unroll
    for (int kc = 0; kc < 2; ++kc) {
      bf16x8 af, bfr[4];
      {
        int r = l15;
        int gi = (k0 >> 3) + kc * 4 + l4;
        int gis = (gi & ~7) | ((gi & 7) ^ (r & 7));
        af = *(const bf16x8*)&AsM[r * 256 + gis * 8];
      }
#pragma unroll
      for (int ni = 0; ni < 4; ++ni) {
        int r = wave * 64 + ni * 16 + l15;
        int G = kc * 4 + l4;
        bfr[ni] = *(const bf16x8*)((char*)Bs + r * 128 + ((G ^ (r & 7)) << 4));
      }
#pragma unroll
      for (int ni = 0; ni < 4; ++ni)
        acc[ni] = __builtin_amdgcn_mfma_f32_16x16x32_bf16(
            af, bfr[ni], acc[ni], 0, 0, 0);
    }
    __syncthreads();
  }

  // ---- row LayerNorm across the 4 waves ----
#pragma unroll
  for (int j = 0; j < 4; ++j) {
    float s = acc[0][j] + acc[1][j] + acc[2][j] + acc[3][j];
    float q = acc[0][j] * acc[0][j] + acc[1][j] * acc[1][j] +
              acc[2][j] * acc[2][j] + acc[3][j] * acc[3][j];
#pragma unroll
    for (int m = 1; m < 16; m <<= 1) {
      s += __shfl_xor(s, m);
      q += __shfl_xor(q, m);
    }
    if (l15 == 0) {
      int row = l4 * 4 + j;
      partS[wave][row] = s;
      partQ[wave][row] = q;
    }
  }
  __syncthreads();

  float mu[4], rsv[4];
#pragma unroll
  for (int j = 0; j < 4; ++j) {
    int row = l4 * 4 + j;
    float s = partS[0][row] + partS[1][row] + partS[2][row] + partS[3][row];
    float q2 = partQ[0][row] + partQ[1][row] + partQ[2][row] + partQ[3][row];
    float m_ = s * (1.f / 256.f);
    float var = q2 * (1.f / 256.f) - m_ * m_;
    mu[j] = m_;
    rsv[j] = rsqrtf(var + 1e-5f);
  }

#pragma unroll
  for (int ni = 0; ni < 4; ++ni)
#pragma unroll
    for (int j = 0; j < 4; ++j) {
      int row = l4 * 4 + j;
      int col2 = wave * 64 + ni * 16 + l15;
      float vv = (acc[ni][j] - mu[j]) * rsv[j] * gS[col2] + bS[col2];
      msgln[(size_t)(bm + row) * 256 + col2] = f2bf(vv);
    }
}

// --- Fused GEMM + row LayerNorm (+bf16 residual). BM=32, grid 600. ---------
template <int KDIM, bool RESID, bool OUTBF>
__global__ __launch_bounds__(256) void gemm_ln_kernel(
    const ushort_t* __restrict__ A, const ushort_t* __restrict__ W,
    const float* __restrict__ g, const float* __restrict__ bb,
    const ushort_t* __restrict__ residb, void* __restrict__ outp) {
  __shared__ char As[32 * 128];
  __shared__ char Bs[256 * 128];
  __shared__ float partS[4][32];
  __shared__ float partQ[4][32];
  __shared__ float gS[256], bS[256];

  const int tid = threadIdx.x;
  const int wave = tid >> 6, lane = tid & 63;
  const int l15 = lane & 15, l4 = lane >> 4;
  const int bm = blockIdx.x * 32;

  gS[tid] = g[tid];
  bS[tid] = bb[tid];

  f32x4 acc[2][4];
#pragma unroll
  for (int i = 0; i < 2; ++i)
#pragma unroll
    for (int j = 0; j < 4; ++j) acc[i][j] = (f32x4){0.f, 0.f, 0.f, 0.f};

  for (int k0 = 0; k0 < KDIM; k0 += 64) {
    {
      int row = tid >> 3, gch = tid & 7;
      const ushort_t* src =
          A + (size_t)(bm + row) * KDIM + k0 + ((gch ^ (row & 7)) << 3);
      GLOAD16(src, As + tid * 16);
    }
#pragma unroll
    for (int c = 0; c < 8; ++c) {
      int ch = c * 256 + tid;
      int row = ch >> 3, gch = ch & 7;
      const ushort_t* src =
          W + (size_t)row * KDIM + k0 + ((gch ^ (row & 7)) << 3);
      GLOAD16(src, Bs + ch * 16);
    }
    __syncthreads();
#pragma unroll
    for (int kc = 0; kc < 2; ++kc) {
      bf16x8 af[2], bfr[4];
#pragma unroll
      for (int mi = 0; mi < 2; ++mi) {
        int r = mi * 16 + l15;
        int G = kc * 4 + l4;
        af[mi] = *(const bf16x8*)(As + r * 128 + ((G ^ (r & 7)) << 4));
      }
#pragma unroll
      for (int ni = 0; ni < 4; ++ni) {
        int r = wave * 64 + ni * 16 + l15;
        int G = kc * 4 + l4;
        bfr[ni] = *(const bf16x8*)(Bs + r * 128 + ((G ^ (r & 7)) << 4));
      }
#pragma unroll
      for (int mi = 0; mi < 2; ++mi)
#pragma unroll
        for (int ni = 0; ni < 4; ++ni)
          acc[mi][ni] = __builtin_amdgcn_mfma_f32_16x16x32_bf16(
              af[mi], bfr[ni], acc[mi][ni], 0, 0, 0);
    }
    __syncthreads();
  }

#pragma unroll
  for (int mi = 0; mi < 2; ++mi)
#pragma unroll
    for (int j = 0; j < 4; ++j) {
      float s = acc[mi][0][j] + acc[mi][1][j] + acc[mi][2][j] + acc[mi][3][j];
      float q = acc[mi][0][j] * acc[mi][0][j] + acc[mi][1][j] * acc[mi][1][j] +
                acc[mi][2][j] * acc[mi][2][j] + acc[mi][3][j] * acc[mi][3][j];
#pragma unroll
      for (int m = 1; m < 16; m <<= 1) {
        s += __shfl_xor(s, m);
        q += __shfl_xor(q, m);
      }
      if (l15 == 0) {
        int row = mi * 16 + l4 * 4 + j;
        partS[wave][row] = s;
        partQ[wave][row] = q;
      }
    }
  __syncthreads();

  float mu[2][4], rsv[2][4];
#pragma unroll
  for (int mi = 0; mi < 2; ++mi)
#pragma unroll
    for (int j = 0; j < 4; ++j) {
      int row = mi * 16 + l4 * 4 + j;
      float s = partS[0][row] + partS[1][row] + partS[2][row] + partS[3][row];
      float q2 = partQ[0][row] + partQ[1][row] + partQ[2][row] + partQ[3][row];
      float m_ = s * (1.f / 256.f);
      float var = q2 * (1.f / 256.f) - m_ * m_;
      mu[mi][j] = m_;
      rsv[mi][j] = rsqrtf(var + 1e-5f);
    }

#pragma unroll
  for (int mi = 0; mi < 2; ++mi)
#pragma unroll
    for (int ni = 0; ni < 4; ++ni)
#pragma unroll
      for (int j = 0; j < 4; ++j) {
        int row = mi * 16 + l4 * 4 + j;
        int col = wave * 64 + ni * 16 + l15;
        float v = (acc[mi][ni][j] - mu[mi][j]) * rsv[mi][j] * gS[col] + bS[col];
        size_t gr = (size_t)(bm + row);
        if (RESID) v += bf2f(residb[gr * 256 + col]);
        if (OUTBF)
          ((ushort_t*)outp)[gr * 256 + col] = f2bf(v);
        else
          ((float*)outp)[gr * 256 + col] = v;
      }
}

// ---- KV = sum_s phi(rot(K))^T V via device-scope atomics into KVt ---------
// grid 1600 = 32 (n,h) x 50 chunks of 96 s-rows. Output KVt[nh][v*32+d] f32.
__global__ __launch_bounds__(256) void kv_partial(
    const ushort_t* __restrict__ Kb, const ushort_t* __restrict__ Vb,
    const float* __restrict__ s_pe,
    float* __restrict__ KVt, float* __restrict__ Ksum) {
  __shared__ float bufK[32][32];
  __shared__ float bufV[32][32];
  const int b = blockIdx.x;
  const int ch = b % KV_CHUNKS;
  const int nh = b / KV_CHUNKS;
  const int h = nh & 7, n = nh >> 3;
  const int tid = threadIdx.x;
  const int d = tid >> 3, vb = (tid & 7) * 4;
  const int half = tid >> 7, t = tid & 127;
  const int srow = t >> 2, seg = (t & 3) * 8;
  const int segS = (seg + 8 * (srow & 3)) & 31;
  float a0 = 0.f, a1 = 0.f, a2 = 0.f, a3 = 0.f, ks = 0.f;
  const size_t base = (size_t)n * SLEN * 256 + (size_t)h * 32;
  const int s0 = ch * KV_SC;
  for (int s = s0; s < s0 + KV_SC; s += 32) {
    __syncthreads();
    const size_t eoff = base + (size_t)(s + srow) * 256 + seg;
    ushort8 u = *(const ushort8*)((half ? Vb : Kb) + eoff);
    float v[8];
#pragma unroll
    for (int i = 0; i < 8; ++i) v[i] = bf2f((ushort_t)u[i]);
    if (!half) {
      const float4* pp = (const float4*)&s_pe[eoff * 2];
      float4 p0 = pp[0], p1 = pp[1], p2 = pp[2], p3 = pp[3];
      float r[8];
      r[0] = v[0] * p0.x - v[1] * p0.y; r[1] = v[1] * p0.z + v[0] * p0.w;
      r[2] = v[2] * p1.x - v[3] * p1.y; r[3] = v[3] * p1.z + v[2] * p1.w;
      r[4] = v[4] * p2.x - v[5] * p2.y; r[5] = v[5] * p2.z + v[4] * p2.w;
      r[6] = v[6] * p3.x - v[7] * p3.y; r[7] = v[7] * p3.z + v[6] * p3.w;
#pragma unroll
      for (int i = 0; i < 8; ++i)
        v[i] = r[i] > 0.f ? r[i] + 1.f : __expf(r[i]);
    }
    float* dst = half ? &bufV[srow][segS] : &bufK[srow][segS];
    *(float4*)dst = (float4){v[0], v[1], v[2], v[3]};
    *(float4*)(dst + 4) = (float4){v[4], v[5], v[6], v[7]};
    __syncthreads();
#pragma unroll
    for (int ss = 0; ss < 32; ++ss) {
      int rot = 8 * (ss & 3);
      float kd = bufK[ss][(d + rot) & 31];
      float4 vv = *(const float4*)&bufV[ss][(vb + rot) & 31];
      a0 += kd * vv.x; a1 += kd * vv.y; a2 += kd * vv.z; a3 += kd * vv.w;
      ks += kd;
    }
  }
  // transposed accumulate: KVt[nh][v*32 + d]
  float* kvh = &KVt[(size_t)nh * 1024 + d];
  atomicAdd(kvh + (vb + 0) * 32, a0);
  atomicAdd(kvh + (vb + 1) * 32, a1);
  atomicAdd(kvh + (vb + 2) * 32, a2);
  atomicAdd(kvh + (vb + 3) * 32, a3);
  if ((tid & 7) == 0) atomicAdd(&Ksum[nh * 32 + d], ks);
}

// -- fp32->bf16 conversions + KVt/Ksum zeroing, one dispatch -----------------
// blocks [0,4800): x/src; [4800,5440): weights; [5440,5473): zero KVt+Ksum.
__global__ __launch_bounds__(256) void conv_all(
    const float* __restrict__ x, const float* __restrict__ src,
    const float* w0, const float* w1, const float* w2, const float* w3,
    const float* w4, const float* w5,
    ushort_t* __restrict__ xo, ushort_t* __restrict__ so,
    ushort_t* o0, ushort_t* o1, ushort_t* o2, ushort_t* o3, ushort_t* o4,
    ushort_t* o5, float* __restrict__ kvz) {
  int blk = blockIdx.x;
  if (blk < 4800) {
    const float* s; ushort_t* d;
    if (blk < 2400) { s = x; d = xo; } else { s = src; d = so; blk -= 2400; }
    size_t o = ((size_t)blk * 256 + threadIdx.x) * 8;
    float4 v0 = *(const float4*)&s[o];
    float4 v1 = *(const float4*)&s[o + 4];
    ushort8 u = {f2bf(v0.x), f2bf(v0.y), f2bf(v0.z), f2bf(v0.w),
                 f2bf(v1.x), f2bf(v1.y), f2bf(v1.z), f2bf(v1.w)};
    *(ushort8*)&d[o] = u;
  } else if (blk < 5440) {
    int e = ((blk - 4800) * 256 + threadIdx.x) * 4;
    const float* s; ushort_t* d; int off;
    if      (e < 65536)  { s = w0; d = o0; off = e; }
    else if (e < 131072) { s = w1; d = o1; off = e - 65536; }
    else if (e < 196608) { s = w2; d = o2; off = e - 131072; }
    else if (e < 262144) { s = w3; d = o3; off = e - 196608; }
    else if (e < 524288) { s = w4; d = o4; off = e - 262144; }
    else                 { s = w5; d = o5; off = e - 524288; }
    float4 v = *(const float4*)&s[off];
    ushort4 u = make_ushort4(f2bf(v.x), f2bf(v.y), f2bf(v.z), f2bf(v.w));
    *(ushort4*)&d[off] = u;
  } else {
    // zero KVt (32768) + Ksum (1024) = 33792 f32 = 33 blocks x 1024
    int e = ((blk - 5440) * 256 + threadIdx.x) * 4;
    *(float4*)&kvz[e] = (float4){0.f, 0.f, 0.f, 0.f};
  }
}

extern "C" void kernel_launch(void* const* d_in, const int* in_sizes, int n_in,
                              void* d_out, int out_size, void* d_ws,
                              size_t ws_size, hipStream_t stream) {
  const float* x    = (const float*)d_in[0];
  const float* src  = (const float*)d_in[1];
  const float* x_pe = (const float*)d_in[2];
  const float* s_pe = (const float*)d_in[3];
  const float* Wq = (const float*)d_in[4];
  const float* Wk = (const float*)d_in[5];
  const float* Wv = (const float*)d_in[6];
  const float* Wm = (const float*)d_in[7];
  const float* W1 = (const float*)d_in[8];
  const float* W2 = (const float*)d_in[9];
  const float* g1 = (const float*)d_in[10];
  const float* b1 = (const float*)d_in[11];
  const float* g2 = (const float*)d_in[12];
  const float* b2 = (const float*)d_in[13];
  float* out = (float*)d_out;

  const size_t R = (size_t)NROWS * 256;  // 4,915,200
  ushort_t* xb    = (ushort_t*)d_ws;
  ushort_t* srcb  = xb + R;
  ushort_t* Qb    = srcb + R;
  ushort_t* Kb    = Qb + R;
  ushort_t* Vb    = Kb + R;
  ushort_t* msgln = Vb + R;
  ushort_t* Wqb   = msgln + R;
  ushort_t* Wkb   = Wqb + 65536;
  ushort_t* Wvb   = Wkb + 65536;
  ushort_t* Wmb   = Wvb + 65536;
  ushort_t* W1b   = Wmb + 65536;
  ushort_t* W2b   = W1b + 262144;
  float* KVt      = (float*)(W2b + 131072);   // 32768 f32 (atomic accum)
  float* Ksum     = KVt + 32768;              // 1024 f32 (atomic accum)
  ushort_t* h1   = Kb;     // Kb+Vb dead after kv_partial (2R contiguous)

  dim3 blk(256);
  // conversions + zero KVt/Ksum for this call's atomics
  conv_all<<<5473, blk, 0, stream>>>(x, src, Wq, Wk, Wv, Wm, W1, W2,
                                     xb, srcb, Wqb, Wkb, Wvb, Wmb, W1b, W2b,
                                     KVt);
  // q,k,v pure GEMMs (single-buffer, 4 blocks/CU)
  qkv_fused<<<900, blk, 35840, stream>>>(xb, srcb, Wqb, Wkb, Wvb, Qb, Kb, Vb);
  // KV/Ksum: rotary+phi fused on K staging; atomic accumulate (no reduce pass)
  kv_partial<<<1600, blk, 0, stream>>>(Kb, Vb, s_pe, KVt, Ksum);
  // FUSED: msg (MFMA) + merge GEMM + LN1 -> msgln (bf16)
  msg_merge_ln<<<1200, blk, 0, stream>>>(Qb, x_pe, KVt, Ksum, Wmb, g1, b1,
                                         msgln);
  // MLP1: h1 = relu([xb, msgln] @ W1.T) (bf16, [19200,512])
  mlp1_kernel<<<600, blk, 35840, stream>>>(xb, msgln, W1b, h1);
  // MLP2 + LN2 + residual(bf16 xb): out = xb + LN(h1 @ W2.T) (fp32)
  gemm_ln_kernel<512, true, false><<<600, blk, 0, stream>>>(
      h1, W2b, g2, b2, xb, out);
}